// Round 6
// baseline (543.851 us; speedup 1.0000x reference)
//
#include <hip/hip_runtime.h>
#include <hip/hip_bf16.h>

// out[b,s,o] = sum_d WHT(x)[b,s,d] * W[o,d] + bias[o]
// M = 8192, K = 4096, N = 4096. GEMM is B^T layout (W rows k-contiguous).

#define D_DIM 4096
#define M_ROWS 8192

typedef float f32x4 __attribute__((ext_vector_type(4)));
typedef float f32x16 __attribute__((ext_vector_type(16)));
typedef __bf16 bf16x8 __attribute__((ext_vector_type(8)));

__device__ __forceinline__ unsigned short f2bf(float f) {
  unsigned int u = __float_as_uint(f);
  return (unsigned short)((u + 0x7fffu + ((u >> 16) & 1u)) >> 16);
}

__device__ __forceinline__ void async16(const void* g, void* l) {
  __builtin_amdgcn_global_load_lds(
      (const __attribute__((address_space(1))) unsigned int*)g,
      (__attribute__((address_space(3))) unsigned int*)l, 16, 0, 0);
}

// ---------------------------------------------------------------------------
// Kernel 1: per-row 4096-point WHT (normalized), fp32 in, bf16 out. Unchanged.
// ---------------------------------------------------------------------------
#define WHT_AS 280
#define WHT_BS 17

__global__ __launch_bounds__(256) void wht_cast_rows(
    const float* __restrict__ X, unsigned short* __restrict__ Y) {
  __shared__ float s[16 * WHT_AS];
  const int row = blockIdx.x;
  const float* xr = X + (size_t)row * D_DIM;
  const int t = threadIdx.x;
  float v[16];

#pragma unroll
  for (int a = 0; a < 16; ++a) v[a] = xr[a * 256 + t];
#pragma unroll
  for (int h = 1; h < 16; h <<= 1) {
#pragma unroll
    for (int i = 0; i < 16; ++i) {
      if ((i & h) == 0) {
        float p = v[i], q = v[i + h];
        v[i] = p + q;
        v[i + h] = p - q;
      }
    }
  }
  {
    const int base = (t >> 4) * WHT_BS + (t & 15);
#pragma unroll
    for (int a = 0; a < 16; ++a) s[a * WHT_AS + base] = v[a];
  }
  __syncthreads();

  {
    const int base = (t >> 4) * WHT_AS + (t & 15);
#pragma unroll
    for (int b = 0; b < 16; ++b) v[b] = s[base + b * WHT_BS];
#pragma unroll
    for (int h = 1; h < 16; h <<= 1) {
#pragma unroll
      for (int i = 0; i < 16; ++i) {
        if ((i & h) == 0) {
          float p = v[i], q = v[i + h];
          v[i] = p + q;
          v[i + h] = p - q;
        }
      }
    }
#pragma unroll
    for (int b = 0; b < 16; ++b) s[base + b * WHT_BS] = v[b];
  }
  __syncthreads();

  {
    const int base = (t >> 4) * WHT_AS + (t & 15) * WHT_BS;
#pragma unroll
    for (int c = 0; c < 16; ++c) v[c] = s[base + c];
#pragma unroll
    for (int h = 1; h < 16; h <<= 1) {
#pragma unroll
      for (int i = 0; i < 16; ++i) {
        if ((i & h) == 0) {
          float p = v[i], q = v[i + h];
          v[i] = p + q;
          v[i + h] = p - q;
        }
      }
    }
    union {
      unsigned short us[16];
      uint4 q4[2];
    } pk;
#pragma unroll
    for (int c = 0; c < 16; ++c) pk.us[c] = f2bf(v[c] * 0.015625f);
    uint4* dst =
        (uint4*)(Y + (size_t)row * D_DIM + (t >> 4) * 256 + (t & 15) * 16);
    dst[0] = pk.q4[0];
    dst[1] = pk.q4[1];
  }
}

// ---------------------------------------------------------------------------
// Kernel 2: W fp32 -> bf16 cast. Unchanged.
// ---------------------------------------------------------------------------
__global__ __launch_bounds__(256) void cast_w(const float* __restrict__ W,
                                              unsigned short* __restrict__ Wb) {
  const size_t i = ((size_t)blockIdx.x * 256 + threadIdx.x) * 8;
  const float4* p = (const float4*)(W + i);
  float4 f0 = p[0], f1 = p[1];
  union {
    unsigned short us[8];
    uint4 q;
  } pk;
  pk.us[0] = f2bf(f0.x);
  pk.us[1] = f2bf(f0.y);
  pk.us[2] = f2bf(f0.z);
  pk.us[3] = f2bf(f0.w);
  pk.us[4] = f2bf(f1.x);
  pk.us[5] = f2bf(f1.y);
  pk.us[6] = f2bf(f1.z);
  pk.us[7] = f2bf(f1.w);
  *(uint4*)(Wb + i) = pk.q;
}

// ---------------------------------------------------------------------------
// Kernel 3: 256x256 bf16 GEMM (B^T) + bias — 4-wave, 128x128/wave, 32x32x16.
//  Rationale (R5 counters): old 8-wave/16x16 structure ran pipes SERIALLY:
//  MFMA 2483 + LDS-read 1536..2300 + write 512 ~= 5280 cyc/tile = measured.
//  This version cuts LDS reads 33% (each half-tile read by 2 waves, not 4/2
//  avg 3) and uses the faster 32x32 pipe (2382 vs 2075 TF ceiling), with
//  only 2 barriers/tile and NO intra-tile barriers (ILP overlaps reads
//  under MFMA; 1 wave/SIMD, acc=256 regs, launch_bounds(256,1)).
//
//  LDS (128 KiB): 2 buf x { A: 256r x 64k, B: 256r x 64k } bf16,
//  row stride 64 shorts (128 B). Swizzle: 16B chunk index ^= (row & 7)
//  -> frag reads (lane l: row=l&31, chunk=(2*ks)|(l>>5)) are conflict-free
//  (bank group = chunk only; 8 lanes per 4-bank group = b128 floor).
//  global_load_lds writes LINEAR dest; swizzle applied by pre-permuting the
//  per-lane GLOBAL source column (both-sides-or-neither, rule 21):
//    thread t stages 16B to LDS (row=p*32+(t>>3), chunkL=t&7) whose data is
//    global col 8*((t&7)^((t>>3)&7)) of that row. Round-trip verified:
//    read chunkL = ((2ks)|(l>>5))^(l&7); orig = chunkL^(row&7) = (2ks)|(l>>5).
//
//  Per K-tile (BK=64): 4 ks-groups; group = {8 ds_read_b128 (next ks),
//  16 MFMA 32x32x16}. Tile boundary: lgkm(0); barrier; stage T+2 -> buf cur
//  (16 async16); vmcnt(16) [T+1 landed, T+2 in flight, one full tile slack];
//  barrier; read ks0 of T+1 from buf^1.
//
//  32x32x16 layouts: A/B: row|n = lane&31, k = (lane>>5)*8 + j (mirrored
//  sourcing, same rule as verified 16x16x32 kernel; shared k-permutation
//  cancels). C/D (HW-verified m74/m101): col = lane&31,
//  row = (reg&3) + 8*(reg>>2) + 4*(lane>>5).
// ---------------------------------------------------------------------------
#define GNT 64  // K / BK

__global__ __launch_bounds__(256, 1) void gemm256_w4(
    const unsigned short* __restrict__ A,  // [M][K] bf16 (x rotated)
    const unsigned short* __restrict__ B,  // [N][K] bf16 (W)
    const float* __restrict__ bias, float* __restrict__ C) {
  constexpr int K = 4096, N = 4096;
  __shared__ unsigned short sm[65536];  // 128 KiB

  const int t = threadIdx.x;
  const int l = t & 63;
  const int w = t >> 6;   // wave 0..3
  const int wr = w >> 1;  // wave row 0..1 (128 rows)
  const int wc = w & 1;   // wave col 0..1 (128 cols)
  const int r31 = l & 31;
  const int hi = l >> 5;  // 0..1
  const int e = l & 7;

  // T1: bijective XCD swizzle (512 % 8 == 0)
  const int orig = blockIdx.x;
  const int wgid = (orig & 7) * 64 + (orig >> 3);
  const int bn = wgid & 15;  // N/256 = 16
  const int bm = wgid >> 4;  // M/256 = 32
  const int m0 = bm * 256, n0 = bn * 256;

  // --- staging: thread t -> LDS row (t>>3) of each 32-row piece, chunk t&7;
  //     global source col pre-permuted by the swizzle.
  const int scol = 8 * ((t & 7) ^ ((t >> 3) & 7));
  const unsigned short* aS = A + (size_t)(m0 + (t >> 3)) * K + scol;
  const unsigned short* bS = B + (size_t)(n0 + (t >> 3)) * K + scol;
  const int dstBase = t * 8;  // shorts

#define STG_T(BUF, KT)                                                    \
  do {                                                                    \
    _Pragma("unroll") for (int p = 0; p < 8; ++p)                         \
        async16(aS + (size_t)(p * 32) * K + (KT)*64,                      \
                &sm[(BUF)*32768 + p * 2048 + dstBase]);                   \
    _Pragma("unroll") for (int p = 0; p < 8; ++p)                         \
        async16(bS + (size_t)(p * 32) * K + (KT)*64,                      \
                &sm[(BUF)*32768 + 16384 + p * 2048 + dstBase]);           \
  } while (0)

  // --- ds_read lane offsets: addr = base + (rowbase + r31)*64 + cks[ks]
  //     cks[ks] = (((ks<<1) | hi) ^ e) * 8 shorts (16B chunk, swizzled)
  int cks[4];
#pragma unroll
  for (int k = 0; k < 4; ++k) cks[k] = (((k << 1) | hi) ^ e) * 8;
  const int aoff = (wr * 128 + r31) * 64;
  const int boff = 16384 + (wc * 128 + r31) * 64;

  f32x16 acc[4][4];
#pragma unroll
  for (int i = 0; i < 4; ++i)
#pragma unroll
    for (int j = 0; j < 4; ++j)
#pragma unroll
      for (int r = 0; r < 16; ++r) acc[i][j][r] = 0.f;

  bf16x8 afr[2][4], bfr[2][4];  // ping-pong operand sets (static indices)

#define RD_FRAGS(P, KS, BASE)                                             \
  do {                                                                    \
    _Pragma("unroll") for (int mf = 0; mf < 4; ++mf) afr[P][mf] =         \
        *(const bf16x8*)&sm[(BASE) + aoff + mf * 2048 + cks[KS]];         \
    _Pragma("unroll") for (int nf = 0; nf < 4; ++nf) bfr[P][nf] =         \
        *(const bf16x8*)&sm[(BASE) + boff + nf * 2048 + cks[KS]];         \
  } while (0)

#define MFMA_KS(P)                                                        \
  do {                                                                    \
    _Pragma("unroll") for (int mf = 0; mf < 4; ++mf)                      \
        _Pragma("unroll") for (int nf = 0; nf < 4; ++nf) acc[mf][nf] =    \
            __builtin_amdgcn_mfma_f32_32x32x16_bf16(                      \
                afr[P][mf], bfr[P][nf], acc[mf][nf], 0, 0, 0);            \
  } while (0)

  // Prologue: tile0 -> buf0, tile1 -> buf1; wait tile0; read its ks0.
  STG_T(0, 0);
  STG_T(1, 1);
  asm volatile("s_waitcnt vmcnt(16)" ::: "memory");  // tile0 landed
  __builtin_amdgcn_s_barrier();
  RD_FRAGS(0, 0, 0);

  int cur = 0;
  for (int T = 0; T < GNT; ++T) {
    const int base = cur * 32768;

    // 4 ks-groups, reads one ks ahead, no barriers in between (pure ILP)
    RD_FRAGS(1, 1, base);
    MFMA_KS(0);
    RD_FRAGS(0, 2, base);
    MFMA_KS(1);
    RD_FRAGS(1, 3, base);
    MFMA_KS(0);
    MFMA_KS(1);

    // Tile boundary: 2 barriers, 1 counted vmcnt.
    asm volatile("s_waitcnt lgkmcnt(0)" ::: "memory");
    __builtin_amdgcn_s_barrier();  // all waves done reading buf[cur]
    if (T + 2 < GNT) STG_T(cur, T + 2);
    if (T < GNT - 2)
      asm volatile("s_waitcnt vmcnt(16)" ::: "memory");  // T+1 landed,
    else                                                 // T+2 in flight
      asm volatile("s_waitcnt vmcnt(0)" ::: "memory");   // tail drain
    __builtin_amdgcn_s_barrier();  // T+1 visible to all waves
    if (T + 1 < GNT) RD_FRAGS(0, 0, base ^ 32768);
    cur ^= 1;
  }

  // Epilogue: col = lane&31, row = (reg&3) + 8*(reg>>2) + 4*hi
  const int mb = m0 + wr * 128;
  const int ncol = n0 + wc * 128 + r31;
  float bv[4];
#pragma unroll
  for (int nf = 0; nf < 4; ++nf) bv[nf] = bias[ncol + nf * 32];
#pragma unroll
  for (int mf = 0; mf < 4; ++mf)
#pragma unroll
    for (int nf = 0; nf < 4; ++nf)
#pragma unroll
      for (int j = 0; j < 16; ++j) {
        const int row = mb + mf * 32 + (j & 3) + ((j >> 2) << 3) + (hi << 2);
        C[(size_t)row * N + ncol + nf * 32] = acc[mf][nf][j] + bv[nf];
      }
}

// ---------------------------------------------------------------------------
extern "C" void kernel_launch(void* const* d_in, const int* in_sizes, int n_in,
                              void* d_out, int out_size, void* d_ws,
                              size_t ws_size, hipStream_t stream) {
  const float* x = (const float*)d_in[0];
  const float* W = (const float*)d_in[1];
  const float* b = (const float*)d_in[2];
  float* out = (float*)d_out;

  unsigned short* Xr = (unsigned short*)d_ws;        // 64 MiB bf16
  unsigned short* Wb = Xr + (size_t)M_ROWS * D_DIM;  // 32 MiB bf16

  wht_cast_rows<<<M_ROWS, 256, 0, stream>>>(x, Xr);
  cast_w<<<(D_DIM * (size_t)D_DIM / 8) / 256, 256, 0, stream>>>(W, Wb);
  // 256x256 tiles: (8192/256) * (4096/256) = 32*16 = 512 blocks
  gemm256_w4<<<512, 256, 0, stream>>>(Xr, Wb, b, out);
}